// Round 9
// baseline (262.593 us; speedup 1.0000x reference)
//
#include <hip/hip_runtime.h>
#include <hip/hip_bf16.h>

// AngleProtoLoss: loss = -mean_n logsoftmax(clip(cos(last_n,cent_k),1e-6)*w+b)[n,n]
// Identity: loss_n = ln2*(log2(sum_k 2^{z_nk}) - z_nn), z = clamp(cos*w*log2e); b cancels.
// k1: centroids+norms -> unit cent (bf16), w*log2e-prescaled unit last (bf16), fp32 z_nn.
// k2: grid (32,32) x 512 thr = 1024 blocks @ 4 blocks/CU (lb(512,8), 32 waves/CU).
//     8 waves x 32 rows (a[2][4], 56 VGPR, no spill), 4 iters of 64-col slabs,
//     2x16KB LDS dbuf, XOR chunk swizzle, one-sided exp-domain clamp.
//     Fused loss tail via waitcnt-only ticket (NO threadfence; R1's wbl2 storm avoided).
// LEDGER (R8 probe, counters finally in hand): steady-state k2: MfmaUtil 31%,
//     VALUBusy 42%, Occ 32% (=10 waves/CU; 2 blk/CU caps at 50%), FETCH 9.3MB, 0 LDS
//     conflicts -> latency-bound, not pipe-bound. Occupancy is the lever this round.
// R3 re-diagnosis (via R6): "1024 blocks thrash L2" was FALSE -- a[4][4]@VGPR64 spill
//     (WRITE 170MB scratch). a[2][4] at 4 blk/CU is untested until now.
// R1: per-block __threadfence()+ticket = 73us serialization. R8: waitcnt-only OK.
// Tripwires: k2 FETCH>>25MB or WRITE>>4MB -> revert grid (32,16); total ~105 -> attack
//     exp2/VALU epilogue instead.

typedef __attribute__((ext_vector_type(8))) short short8;
typedef __attribute__((ext_vector_type(4))) float f32x4;

#define NSPK 8192
#define DEMB 128
#define MUTT 10
#define LOG2E 1.44269504088896340736f
#define LN2   0.69314718055994530942f

// workspace floats: [0,8192)=zdiag, [8192,16384)=zsum; then bf16 matrices; ticket after.
#define WS_ZDIAG 0
#define WS_ZSUM  8192
#define WS_LASTB 65536      // byte offset, 2 MB
#define WS_CENTB 2162688    // byte offset, 2 MB
#define WS_TICKET 1073152   // int idx (byte 4292608)

__global__ __launch_bounds__(256) void k1_prep(const float* __restrict__ x,
                                               const float* __restrict__ wp,
                                               float* __restrict__ W,
                                               __hip_bfloat16* __restrict__ lastb,
                                               __hip_bfloat16* __restrict__ centb) {
    const int wv = threadIdx.x >> 6;
    const int l  = threadIdx.x & 63;
    const int n  = blockIdx.x * 4 + wv;           // one wave per speaker
    if (blockIdx.x < 32) W[WS_ZSUM + blockIdx.x * 256 + threadIdx.x] = 0.f;
    if (blockIdx.x == 32 && threadIdx.x == 0) ((int*)W)[WS_TICKET] = 0;

    // flat 1280 floats per speaker; lane l, step i -> float4 at 64*i + l.
    // lanes 0..31: m = 2i ; lanes 32..63: m = 2i+1
    const float4* xr = (const float4*)(x + (size_t)n * (MUTT * DEMB)) + l;
    float4 v[5];
#pragma unroll
    for (int i = 0; i < 5; ++i) v[i] = xr[i * 64];

    float4 cs;
    cs.x = ((v[0].x + v[1].x) + (v[2].x + v[3].x)) + v[4].x;
    cs.y = ((v[0].y + v[1].y) + (v[2].y + v[3].y)) + v[4].y;
    cs.z = ((v[0].z + v[1].z) + (v[2].z + v[3].z)) + v[4].z;
    cs.w = ((v[0].w + v[1].w) + (v[2].w + v[3].w)) + v[4].w;
    cs.x += __shfl_xor(cs.x, 32);
    cs.y += __shfl_xor(cs.y, 32);
    cs.z += __shfl_xor(cs.z, 32);
    cs.w += __shfl_xor(cs.w, 32);
    float4 cent;
    cent.x = cs.x * 0.1f; cent.y = cs.y * 0.1f; cent.z = cs.z * 0.1f; cent.w = cs.w * 0.1f;

    // last row (m=9) lives in v[4] of lanes >= 32; mirror into lanes < 32
    float4 lv = v[4];
    {
        const float tx = __shfl_xor(lv.x, 32);
        const float ty = __shfl_xor(lv.y, 32);
        const float tz = __shfl_xor(lv.z, 32);
        const float tw = __shfl_xor(lv.w, 32);
        if (l < 32) { lv.x = tx; lv.y = ty; lv.z = tz; lv.w = tw; }
    }

    float sl = lv.x * lv.x + lv.y * lv.y + lv.z * lv.z + lv.w * lv.w;
    float sc = cent.x * cent.x + cent.y * cent.y + cent.z * cent.z + cent.w * cent.w;
    float dp = lv.x * cent.x + lv.y * cent.y + lv.z * cent.z + lv.w * cent.w;
#pragma unroll
    for (int off = 1; off < 32; off <<= 1) {
        sl += __shfl_xor(sl, off);
        sc += __shfl_xor(sc, off);
        dp += __shfl_xor(dp, off);
    }
    const float il = rsqrtf(sl), ic = rsqrtf(sc);
    const float scale = wp[0] * LOG2E;
    const float as = il * scale;                  // prescale last by w*log2e

    const float  f  = (l < 32) ? as : ic;
    const float4 s4 = (l < 32) ? lv : cent;
    __hip_bfloat16* bp = ((l < 32) ? lastb : centb) + (size_t)n * DEMB + 4 * (l & 31);
    union { __hip_bfloat162 h[2]; uint2 u; } pk;
    pk.h[0].x = __float2bfloat16(s4.x * f);
    pk.h[0].y = __float2bfloat16(s4.y * f);
    pk.h[1].x = __float2bfloat16(s4.z * f);
    pk.h[1].y = __float2bfloat16(s4.w * f);
    *(uint2*)bp = pk.u;

    if (l == 0) {
        const float lo = scale >= 0.f ? 1e-6f * scale : -INFINITY;
        const float hi = scale >= 0.f ? INFINITY : 1e-6f * scale;
        W[WS_ZDIAG + n] = fminf(fmaxf(dp * il * ic * scale, lo), hi);
    }
}

// grid (32,32) x 512 threads: 256-row block x 256-col chunk. 8 waves; wave owns 32 rows.
__global__ __launch_bounds__(512, 8) void k2_main(
        const __hip_bfloat16* __restrict__ lastb,
        const __hip_bfloat16* __restrict__ centb,
        const float* __restrict__ wp,
        float* __restrict__ zsum,
        const float* __restrict__ zdiag,
        int* __restrict__ ticket,
        float* __restrict__ out) {
    const int tid  = threadIdx.x;
    const int lane = tid & 63;
    const int wv   = tid >> 6;                // 0..7
    const int quad = lane >> 4;
    const int l16  = lane & 15;
    const int R0   = blockIdx.x * 256;
    const int C0   = blockIdx.y * 256;
    const float scale = wp[0] * LOG2E;
    // clamp in exp domain (2^z monotone). scale>=0: e >= c0; scale<0: e <= c0.
    const float c0  = __builtin_amdgcn_exp2f(1e-6f * scale);
    const bool  pos = (scale >= 0.f);

    __shared__ uint4 Bs4[2048];   // 2 x 16 KB double buffer, XOR chunk-swizzled
    __shared__ float redw[8];
    __shared__ int   lastFlag;
    char* Bsc = (char*)Bs4;

    // staging: wave wv stages rows wv*8 + i*4 + quad (i=0,1); LDS image = R0 layout
#pragma unroll
    for (int i = 0; i < 2; ++i) {
        const int rr = wv * 8 + i * 4 + quad;
        const int c  = l16 ^ (rr & 15);
        const char* src = (const char*)centb + ((size_t)(C0 + rr) << 8) + (c << 4);
        char* dst = Bsc + (wv * 2048 + i * 1024 + lane * 16);
        __builtin_amdgcn_global_load_lds(
            (const __attribute__((address_space(1))) unsigned int*)src,
            (__attribute__((address_space(3))) unsigned int*)dst, 16, 0, 0);
    }

    // A fragments (held whole kernel): rows R0 + wv*32 + rt*16 + l16, k = quad*8 + kc*32
    short8 a[2][4];
    {
        const short* ap = (const short*)lastb + (size_t)(R0 + wv * 32 + l16) * DEMB + quad * 8;
#pragma unroll
        for (int rt = 0; rt < 2; ++rt)
#pragma unroll
            for (int kc = 0; kc < 4; ++kc)
                a[rt][kc] = *(const short8*)(ap + rt * 16 * DEMB + kc * 32);
    }

    // swizzled B-fragment byte offsets within a 16-row ntile: row=l16, chunk=(quad+4kc)^l16
    int roff[4];
#pragma unroll
    for (int kc = 0; kc < 4; ++kc)
        roff[kc] = l16 * 256 + (((quad + 4 * kc) ^ l16) << 4);

    float racc[2][4] = {{0.f}};

    for (int it = 0; it < 4; ++it) {
        // drains vmcnt -> DMA(it) landed; also all waves done reading buf[(it+1)&1]
        __syncthreads();
        if (it < 3) {
            const int c0n = C0 + (it + 1) * 64;
            char* bufn = Bsc + ((it + 1) & 1) * 16384;
#pragma unroll
            for (int i = 0; i < 2; ++i) {
                const int rr = wv * 8 + i * 4 + quad;
                const int c  = l16 ^ (rr & 15);
                const char* src = (const char*)centb + ((size_t)(c0n + rr) << 8) + (c << 4);
                char* dst = bufn + (wv * 2048 + i * 1024 + lane * 16);
                __builtin_amdgcn_global_load_lds(
                    (const __attribute__((address_space(1))) unsigned int*)src,
                    (__attribute__((address_space(3))) unsigned int*)dst, 16, 0, 0);
            }
        }
        const char* buf = Bsc + (it & 1) * 16384;
#pragma unroll
        for (int nt = 0; nt < 4; ++nt) {
            short8 b[4];
#pragma unroll
            for (int kc = 0; kc < 4; ++kc)
                b[kc] = *(const short8*)(buf + nt * 4096 + roff[kc]);
            if (pos) {   // wave-uniform: single-sided clamp
#pragma unroll
                for (int rt = 0; rt < 2; ++rt) {
                    f32x4 acc = {0.f, 0.f, 0.f, 0.f};
#pragma unroll
                    for (int kc = 0; kc < 4; ++kc)
                        acc = __builtin_amdgcn_mfma_f32_16x16x32_bf16(a[rt][kc], b[kc], acc, 0, 0, 0);
#pragma unroll
                    for (int r = 0; r < 4; ++r)
                        racc[rt][r] += fmaxf(__builtin_amdgcn_exp2f(acc[r]), c0);
                }
            } else {
#pragma unroll
                for (int rt = 0; rt < 2; ++rt) {
                    f32x4 acc = {0.f, 0.f, 0.f, 0.f};
#pragma unroll
                    for (int kc = 0; kc < 4; ++kc)
                        acc = __builtin_amdgcn_mfma_f32_16x16x32_bf16(a[rt][kc], b[kc], acc, 0, 0, 0);
#pragma unroll
                    for (int r = 0; r < 4; ++r)
                        racc[rt][r] += fminf(__builtin_amdgcn_exp2f(acc[r]), c0);
                }
            }
        }
    }
    // reduce row sums over the 16 l16-lanes holding the same rows
#pragma unroll
    for (int off = 1; off < 16; off <<= 1)
#pragma unroll
        for (int rt = 0; rt < 2; ++rt)
#pragma unroll
            for (int r = 0; r < 4; ++r)
                racc[rt][r] += __shfl_xor(racc[rt][r], off);
    if (l16 == 0) {
#pragma unroll
        for (int rt = 0; rt < 2; ++rt)
#pragma unroll
            for (int r = 0; r < 4; ++r)
                atomicAdd(&zsum[R0 + wv * 32 + rt * 16 + quad * 4 + r], racc[rt][r]);
    }

    // ---- fused loss tail: waitcnt-only ticket (no threadfence / cache maintenance) ----
    // own wave's zsum atomics complete at the coherence point:
    asm volatile("s_waitcnt vmcnt(0)" ::: "memory");
    __syncthreads();                       // => all 8 waves' atomics complete
    if (tid == 0) {
        const int prev = __hip_atomic_fetch_add(ticket, 1, __ATOMIC_RELAXED,
                                                __HIP_MEMORY_SCOPE_AGENT);
        lastFlag = (prev == 32 * 32 - 1);
    }
    __syncthreads();
    if (lastFlag) {                        // block-uniform: last-finishing block
        float v = 0.f;
        for (int n = tid; n < NSPK; n += 512) {
            // fetch_add(0) = coherence-point read of the fully-accumulated zsum
            const float s = __hip_atomic_fetch_add(&zsum[n], 0.f,
                                                   __ATOMIC_RELAXED,
                                                   __HIP_MEMORY_SCOPE_AGENT);
            v += __log2f(s) - zdiag[n];
        }
#pragma unroll
        for (int off = 1; off < 64; off <<= 1) v += __shfl_xor(v, off);
        if (lane == 0) redw[wv] = v;
        __syncthreads();
        if (tid == 0) {
            float t = 0.f;
#pragma unroll
            for (int i = 0; i < 8; ++i) t += redw[i];
            out[0] = t * (LN2 / (float)NSPK);
        }
    }
}

extern "C" void kernel_launch(void* const* d_in, const int* in_sizes, int n_in,
                              void* d_out, int out_size, void* d_ws, size_t ws_size,
                              hipStream_t stream) {
    const float* x = (const float*)d_in[0];
    const float* w = (const float*)d_in[1];
    // b (d_in[2]) cancels analytically — unused.
    float* W = (float*)d_ws;
    __hip_bfloat16* lastb = (__hip_bfloat16*)((char*)d_ws + WS_LASTB);
    __hip_bfloat16* centb = (__hip_bfloat16*)((char*)d_ws + WS_CENTB);

    k1_prep<<<NSPK / 4, 256, 0, stream>>>(x, w, W, lastb, centb);
    k2_main<<<dim3(32, 32), 512, 0, stream>>>(lastb, centb, w, W + WS_ZSUM,
                                              W + WS_ZDIAG, (int*)W + WS_TICKET,
                                              (float*)d_out);
}

// Round 10
// 110.592 us; speedup vs baseline: 2.3744x; 2.3744x over previous
//
#include <hip/hip_runtime.h>
#include <hip/hip_bf16.h>

// AngleProtoLoss: loss = -mean_n logsoftmax(clip(cos(last_n,cent_k),1e-6)*w+b)[n,n]
// Identity: loss_n = ln2*(log2(sum_k 2^{z_nk}) - z_nn), z = clamp(cos*w*log2e); b cancels.
// k1: centroids+norms -> unit cent (bf16), w*log2e-prescaled unit last (bf16), fp32 z_nn.
// k2: R8-proven best: grid (32,16) x 512 thr, lb(512,4) [VGPR 56, no spill], 8 waves x
//     32 rows (a[2][4]), 8 iters of 64-col slabs, 2x16KB LDS dbuf, XOR chunk swizzle,
//     one-sided exp-domain clamp, fused loss tail via waitcnt-only ticket.
//     R8 ledger: real pipeline = 104.7us (148.1 - 43.4 probe). This round: probe removed,
//     nothing else touched.
// EVIDENCE LEDGER:
//   fill 44.5us fixed harness; k1 ~10; k2 ~27-34; steady-state k2 counters (R8 probe):
//   MfmaUtil 31% + VALUBusy 42%, FETCH 9.3MB, 0 LDS conflicts -> ~73% combined busy.
//   Occupancy NOT the lever: R0(8w/CU)=34us, R5(16w/CU, 2x LDS traffic)=35.3us,
//   R7(half barriers)=41us -- time invariant under waves/traffic/barrier count.
//   VGPR law (R3/R6/R9): every "locality" regression was a spill. lb(512,8) caps
//   VGPR@64 -> allocator collapsed to 32, WRITE 297MB scratch, k2 180-30000us.
//   R1: per-block __threadfence()+ticket = wbl2 storm, k2 73us. waitcnt-only OK (R8).

typedef __attribute__((ext_vector_type(8))) short short8;
typedef __attribute__((ext_vector_type(4))) float f32x4;

#define NSPK 8192
#define DEMB 128
#define MUTT 10
#define LOG2E 1.44269504088896340736f
#define LN2   0.69314718055994530942f

// workspace floats: [0,8192)=zdiag, [8192,16384)=zsum; then bf16 matrices; ticket after.
#define WS_ZDIAG 0
#define WS_ZSUM  8192
#define WS_LASTB 65536      // byte offset, 2 MB
#define WS_CENTB 2162688    // byte offset, 2 MB
#define WS_TICKET 1073152   // int idx (byte 4292608)

__global__ __launch_bounds__(256) void k1_prep(const float* __restrict__ x,
                                               const float* __restrict__ wp,
                                               float* __restrict__ W,
                                               __hip_bfloat16* __restrict__ lastb,
                                               __hip_bfloat16* __restrict__ centb) {
    const int wv = threadIdx.x >> 6;
    const int l  = threadIdx.x & 63;
    const int n  = blockIdx.x * 4 + wv;           // one wave per speaker
    if (blockIdx.x < 32) W[WS_ZSUM + blockIdx.x * 256 + threadIdx.x] = 0.f;
    if (blockIdx.x == 32 && threadIdx.x == 0) ((int*)W)[WS_TICKET] = 0;

    // flat 1280 floats per speaker; lane l, step i -> float4 at 64*i + l.
    // lanes 0..31: m = 2i ; lanes 32..63: m = 2i+1
    const float4* xr = (const float4*)(x + (size_t)n * (MUTT * DEMB)) + l;
    float4 v[5];
#pragma unroll
    for (int i = 0; i < 5; ++i) v[i] = xr[i * 64];

    float4 cs;
    cs.x = ((v[0].x + v[1].x) + (v[2].x + v[3].x)) + v[4].x;
    cs.y = ((v[0].y + v[1].y) + (v[2].y + v[3].y)) + v[4].y;
    cs.z = ((v[0].z + v[1].z) + (v[2].z + v[3].z)) + v[4].z;
    cs.w = ((v[0].w + v[1].w) + (v[2].w + v[3].w)) + v[4].w;
    cs.x += __shfl_xor(cs.x, 32);
    cs.y += __shfl_xor(cs.y, 32);
    cs.z += __shfl_xor(cs.z, 32);
    cs.w += __shfl_xor(cs.w, 32);
    float4 cent;
    cent.x = cs.x * 0.1f; cent.y = cs.y * 0.1f; cent.z = cs.z * 0.1f; cent.w = cs.w * 0.1f;

    // last row (m=9) lives in v[4] of lanes >= 32; mirror into lanes < 32
    float4 lv = v[4];
    {
        const float tx = __shfl_xor(lv.x, 32);
        const float ty = __shfl_xor(lv.y, 32);
        const float tz = __shfl_xor(lv.z, 32);
        const float tw = __shfl_xor(lv.w, 32);
        if (l < 32) { lv.x = tx; lv.y = ty; lv.z = tz; lv.w = tw; }
    }

    float sl = lv.x * lv.x + lv.y * lv.y + lv.z * lv.z + lv.w * lv.w;
    float sc = cent.x * cent.x + cent.y * cent.y + cent.z * cent.z + cent.w * cent.w;
    float dp = lv.x * cent.x + lv.y * cent.y + lv.z * cent.z + lv.w * cent.w;
#pragma unroll
    for (int off = 1; off < 32; off <<= 1) {
        sl += __shfl_xor(sl, off);
        sc += __shfl_xor(sc, off);
        dp += __shfl_xor(dp, off);
    }
    const float il = rsqrtf(sl), ic = rsqrtf(sc);
    const float scale = wp[0] * LOG2E;
    const float as = il * scale;                  // prescale last by w*log2e

    const float  f  = (l < 32) ? as : ic;
    const float4 s4 = (l < 32) ? lv : cent;
    __hip_bfloat16* bp = ((l < 32) ? lastb : centb) + (size_t)n * DEMB + 4 * (l & 31);
    union { __hip_bfloat162 h[2]; uint2 u; } pk;
    pk.h[0].x = __float2bfloat16(s4.x * f);
    pk.h[0].y = __float2bfloat16(s4.y * f);
    pk.h[1].x = __float2bfloat16(s4.z * f);
    pk.h[1].y = __float2bfloat16(s4.w * f);
    *(uint2*)bp = pk.u;

    if (l == 0) {
        const float lo = scale >= 0.f ? 1e-6f * scale : -INFINITY;
        const float hi = scale >= 0.f ? INFINITY : 1e-6f * scale;
        W[WS_ZDIAG + n] = fminf(fmaxf(dp * il * ic * scale, lo), hi);
    }
}

// grid (32,16) x 512 threads: 256-row block x 512-col chunk. 8 waves; wave owns 32 rows.
// reps kept for codegen identity with the R8-measured binary (always called with 1).
__global__ __launch_bounds__(512, 4) void k2_main(
        const __hip_bfloat16* __restrict__ lastb,
        const __hip_bfloat16* __restrict__ centb,
        const float* __restrict__ wp,
        float* __restrict__ zsum,
        const float* __restrict__ zdiag,
        int* __restrict__ ticket,
        float* __restrict__ out,
        int reps) {
    const int tid  = threadIdx.x;
    const int lane = tid & 63;
    const int wv   = tid >> 6;                // 0..7
    const int quad = lane >> 4;
    const int l16  = lane & 15;
    const int R0   = blockIdx.x * 256;
    const int C0   = blockIdx.y * 512;
    const float scale = wp[0] * LOG2E;
    // clamp in exp domain (2^z monotone). scale>=0: e >= c0; scale<0: e <= c0.
    const float c0  = __builtin_amdgcn_exp2f(1e-6f * scale);
    const bool  pos = (scale >= 0.f);

    __shared__ uint4 Bs4[2048];   // 2 x 16 KB double buffer, XOR chunk-swizzled
    __shared__ float redw[8];
    __shared__ int   lastFlag;
    char* Bsc = (char*)Bs4;

    // staging: wave wv stages rows wv*8 + i*4 + quad (i=0,1); LDS image = R0 layout
#pragma unroll
    for (int i = 0; i < 2; ++i) {
        const int rr = wv * 8 + i * 4 + quad;
        const int c  = l16 ^ (rr & 15);
        const char* src = (const char*)centb + ((size_t)(C0 + rr) << 8) + (c << 4);
        char* dst = Bsc + (wv * 2048 + i * 1024 + lane * 16);
        __builtin_amdgcn_global_load_lds(
            (const __attribute__((address_space(1))) unsigned int*)src,
            (__attribute__((address_space(3))) unsigned int*)dst, 16, 0, 0);
    }

    // A fragments (held whole kernel): rows R0 + wv*32 + rt*16 + l16, k = quad*8 + kc*32
    short8 a[2][4];
    {
        const short* ap = (const short*)lastb + (size_t)(R0 + wv * 32 + l16) * DEMB + quad * 8;
#pragma unroll
        for (int rt = 0; rt < 2; ++rt)
#pragma unroll
            for (int kc = 0; kc < 4; ++kc)
                a[rt][kc] = *(const short8*)(ap + rt * 16 * DEMB + kc * 32);
    }

    // swizzled B-fragment byte offsets within a 16-row ntile: row=l16, chunk=(quad+4kc)^l16
    int roff[4];
#pragma unroll
    for (int kc = 0; kc < 4; ++kc)
        roff[kc] = l16 * 256 + (((quad + 4 * kc) ^ l16) << 4);

    float racc[2][4] = {{0.f}};

    for (int rep = 0; rep < reps; ++rep) {
        for (int it = 0; it < 8; ++it) {
            // drains vmcnt -> DMA(it) landed; also all waves done reading buf[(it+1)&1]
            __syncthreads();
            if (it < 7 || rep + 1 < reps) {
                const int itn = (it + 1) & 7;
                const int c0n = C0 + itn * 64;
                char* bufn = Bsc + ((it + 1) & 1) * 16384;
#pragma unroll
                for (int i = 0; i < 2; ++i) {
                    const int rr = wv * 8 + i * 4 + quad;
                    const int c  = l16 ^ (rr & 15);
                    const char* src = (const char*)centb + ((size_t)(c0n + rr) << 8) + (c << 4);
                    char* dst = bufn + (wv * 2048 + i * 1024 + lane * 16);
                    __builtin_amdgcn_global_load_lds(
                        (const __attribute__((address_space(1))) unsigned int*)src,
                        (__attribute__((address_space(3))) unsigned int*)dst, 16, 0, 0);
                }
            }
            const char* buf = Bsc + (it & 1) * 16384;
#pragma unroll
            for (int nt = 0; nt < 4; ++nt) {
                short8 b[4];
#pragma unroll
                for (int kc = 0; kc < 4; ++kc)
                    b[kc] = *(const short8*)(buf + nt * 4096 + roff[kc]);
                if (pos) {   // wave-uniform: single-sided clamp
#pragma unroll
                    for (int rt = 0; rt < 2; ++rt) {
                        f32x4 acc = {0.f, 0.f, 0.f, 0.f};
#pragma unroll
                        for (int kc = 0; kc < 4; ++kc)
                            acc = __builtin_amdgcn_mfma_f32_16x16x32_bf16(a[rt][kc], b[kc], acc, 0, 0, 0);
#pragma unroll
                        for (int r = 0; r < 4; ++r)
                            racc[rt][r] += fmaxf(__builtin_amdgcn_exp2f(acc[r]), c0);
                    }
                } else {
#pragma unroll
                    for (int rt = 0; rt < 2; ++rt) {
                        f32x4 acc = {0.f, 0.f, 0.f, 0.f};
#pragma unroll
                        for (int kc = 0; kc < 4; ++kc)
                            acc = __builtin_amdgcn_mfma_f32_16x16x32_bf16(a[rt][kc], b[kc], acc, 0, 0, 0);
#pragma unroll
                        for (int r = 0; r < 4; ++r)
                            racc[rt][r] += fminf(__builtin_amdgcn_exp2f(acc[r]), c0);
                    }
                }
            }
        }
    }
    // reduce row sums over the 16 l16-lanes holding the same rows
#pragma unroll
    for (int off = 1; off < 16; off <<= 1)
#pragma unroll
        for (int rt = 0; rt < 2; ++rt)
#pragma unroll
            for (int r = 0; r < 4; ++r)
                racc[rt][r] += __shfl_xor(racc[rt][r], off);
    if (l16 == 0) {
#pragma unroll
        for (int rt = 0; rt < 2; ++rt)
#pragma unroll
            for (int r = 0; r < 4; ++r)
                atomicAdd(&zsum[R0 + wv * 32 + rt * 16 + quad * 4 + r], racc[rt][r]);
    }

    // ---- fused loss tail: waitcnt-only ticket (no threadfence / cache maintenance) ----
    if (out != nullptr) {
        // own wave's zsum atomics complete at the coherence point:
        asm volatile("s_waitcnt vmcnt(0)" ::: "memory");
        __syncthreads();                       // => all 8 waves' atomics complete
        if (tid == 0) {
            const int prev = __hip_atomic_fetch_add(ticket, 1, __ATOMIC_RELAXED,
                                                    __HIP_MEMORY_SCOPE_AGENT);
            lastFlag = (prev == 32 * 16 - 1);
        }
        __syncthreads();
        if (lastFlag) {                        // block-uniform: last-finishing block
            float v = 0.f;
            for (int n = tid; n < NSPK; n += 512) {
                // fetch_add(0) = coherence-point read of the fully-accumulated zsum
                const float s = __hip_atomic_fetch_add(&zsum[n], 0.f,
                                                       __ATOMIC_RELAXED,
                                                       __HIP_MEMORY_SCOPE_AGENT);
                v += __log2f(s) - zdiag[n];
            }
#pragma unroll
            for (int off = 1; off < 64; off <<= 1) v += __shfl_xor(v, off);
            if (lane == 0) redw[wv] = v;
            __syncthreads();
            if (tid == 0) {
                float t = 0.f;
#pragma unroll
                for (int i = 0; i < 8; ++i) t += redw[i];
                out[0] = t * (LN2 / (float)NSPK);
            }
        }
    }
}

extern "C" void kernel_launch(void* const* d_in, const int* in_sizes, int n_in,
                              void* d_out, int out_size, void* d_ws, size_t ws_size,
                              hipStream_t stream) {
    const float* x = (const float*)d_in[0];
    const float* w = (const float*)d_in[1];
    // b (d_in[2]) cancels analytically — unused.
    float* W = (float*)d_ws;
    __hip_bfloat16* lastb = (__hip_bfloat16*)((char*)d_ws + WS_LASTB);
    __hip_bfloat16* centb = (__hip_bfloat16*)((char*)d_ws + WS_CENTB);

    k1_prep<<<NSPK / 4, 256, 0, stream>>>(x, w, W, lastb, centb);
    k2_main<<<dim3(32, 16), 512, 0, stream>>>(lastb, centb, w, W + WS_ZSUM,
                                              W + WS_ZDIAG, (int*)W + WS_TICKET,
                                              (float*)d_out, 1);
}

// Round 11
// 110.469 us; speedup vs baseline: 2.3771x; 1.0011x over previous
//
#include <hip/hip_runtime.h>
#include <hip/hip_bf16.h>

// AngleProtoLoss: loss = -mean_n logsoftmax(clip(cos(last_n,cent_k),1e-6)*w+b)[n,n]
// Identity: loss_n = ln2*(log2(sum_k 2^{z_nk}) - z_nn), z = clamp(cos*w*log2e); b cancels.
// k1: centroids+norms -> unit cent (bf16), w*log2e-prescaled unit last (bf16), fp32 z_nn.
// k2: R10 structure with ONE change: 2x16KB dbuf + __syncthreads (which drains
//     vmcnt(0) every iter) -> 3x16KB rotation + raw s_barrier + COUNTED vmcnt(2)
//     (T4/m218 pattern): 2 prefetch DMAs stay in flight across every barrier; the
//     full drain happens only at the final iter. STAGE is issued AFTER the barrier
//     (so buf[(it+2)%3]=buf[(it-1)%3] is never overwritten while still being read).
//     Fused loss tail via waitcnt-only ticket unchanged (R8/R10-proven, neutral-cost).
// EVIDENCE LEDGER:
//   fill 44.5us + reset train ~20us harness-fixed; k1 ~8-10 (floor 7); k2 ~22-27
//   (R8 probe marginal 21.7/8-iter pass); k2 pipes: MFMA 8.3, LDS ~10, exp2/VALU ~6
//   per CU -> heaviest ~10 vs ~23 measured => per-iter vmcnt(0) barrier drain is the
//   residual. Tile space exhausted: rt=4 worse (R0 34 vs R5 35.3/R10, occupancy
//   dominates); col-split spills (R6); lb(512,8) collapses VGPR to 32 (R9, 297MB
//   scratch); 1024 blocks without spill-safe regs also bad (R3). R5==R10=110.6.
//   R1: per-block __threadfence()+ticket = wbl2 storm (73us). waitcnt-only ticket OK.

typedef __attribute__((ext_vector_type(8))) short short8;
typedef __attribute__((ext_vector_type(4))) float f32x4;

#define NSPK 8192
#define DEMB 128
#define MUTT 10
#define LOG2E 1.44269504088896340736f
#define LN2   0.69314718055994530942f

// workspace floats: [0,8192)=zdiag, [8192,16384)=zsum; then bf16 matrices; ticket after.
#define WS_ZDIAG 0
#define WS_ZSUM  8192
#define WS_LASTB 65536      // byte offset, 2 MB
#define WS_CENTB 2162688    // byte offset, 2 MB
#define WS_TICKET 1073152   // int idx (byte 4292608)

__global__ __launch_bounds__(256) void k1_prep(const float* __restrict__ x,
                                               const float* __restrict__ wp,
                                               float* __restrict__ W,
                                               __hip_bfloat16* __restrict__ lastb,
                                               __hip_bfloat16* __restrict__ centb) {
    const int wv = threadIdx.x >> 6;
    const int l  = threadIdx.x & 63;
    const int n  = blockIdx.x * 4 + wv;           // one wave per speaker
    if (blockIdx.x < 32) W[WS_ZSUM + blockIdx.x * 256 + threadIdx.x] = 0.f;
    if (blockIdx.x == 32 && threadIdx.x == 0) ((int*)W)[WS_TICKET] = 0;

    // flat 1280 floats per speaker; lane l, step i -> float4 at 64*i + l.
    // lanes 0..31: m = 2i ; lanes 32..63: m = 2i+1
    const float4* xr = (const float4*)(x + (size_t)n * (MUTT * DEMB)) + l;
    float4 v[5];
#pragma unroll
    for (int i = 0; i < 5; ++i) v[i] = xr[i * 64];

    float4 cs;
    cs.x = ((v[0].x + v[1].x) + (v[2].x + v[3].x)) + v[4].x;
    cs.y = ((v[0].y + v[1].y) + (v[2].y + v[3].y)) + v[4].y;
    cs.z = ((v[0].z + v[1].z) + (v[2].z + v[3].z)) + v[4].z;
    cs.w = ((v[0].w + v[1].w) + (v[2].w + v[3].w)) + v[4].w;
    cs.x += __shfl_xor(cs.x, 32);
    cs.y += __shfl_xor(cs.y, 32);
    cs.z += __shfl_xor(cs.z, 32);
    cs.w += __shfl_xor(cs.w, 32);
    float4 cent;
    cent.x = cs.x * 0.1f; cent.y = cs.y * 0.1f; cent.z = cs.z * 0.1f; cent.w = cs.w * 0.1f;

    // last row (m=9) lives in v[4] of lanes >= 32; mirror into lanes < 32
    float4 lv = v[4];
    {
        const float tx = __shfl_xor(lv.x, 32);
        const float ty = __shfl_xor(lv.y, 32);
        const float tz = __shfl_xor(lv.z, 32);
        const float tw = __shfl_xor(lv.w, 32);
        if (l < 32) { lv.x = tx; lv.y = ty; lv.z = tz; lv.w = tw; }
    }

    float sl = lv.x * lv.x + lv.y * lv.y + lv.z * lv.z + lv.w * lv.w;
    float sc = cent.x * cent.x + cent.y * cent.y + cent.z * cent.z + cent.w * cent.w;
    float dp = lv.x * cent.x + lv.y * cent.y + lv.z * cent.z + lv.w * cent.w;
#pragma unroll
    for (int off = 1; off < 32; off <<= 1) {
        sl += __shfl_xor(sl, off);
        sc += __shfl_xor(sc, off);
        dp += __shfl_xor(dp, off);
    }
    const float il = rsqrtf(sl), ic = rsqrtf(sc);
    const float scale = wp[0] * LOG2E;
    const float as = il * scale;                  // prescale last by w*log2e

    const float  f  = (l < 32) ? as : ic;
    const float4 s4 = (l < 32) ? lv : cent;
    __hip_bfloat16* bp = ((l < 32) ? lastb : centb) + (size_t)n * DEMB + 4 * (l & 31);
    union { __hip_bfloat162 h[2]; uint2 u; } pk;
    pk.h[0].x = __float2bfloat16(s4.x * f);
    pk.h[0].y = __float2bfloat16(s4.y * f);
    pk.h[1].x = __float2bfloat16(s4.z * f);
    pk.h[1].y = __float2bfloat16(s4.w * f);
    *(uint2*)bp = pk.u;

    if (l == 0) {
        const float lo = scale >= 0.f ? 1e-6f * scale : -INFINITY;
        const float hi = scale >= 0.f ? INFINITY : 1e-6f * scale;
        W[WS_ZDIAG + n] = fminf(fmaxf(dp * il * ic * scale, lo), hi);
    }
}

// grid (32,16) x 512 threads: 256-row block x 512-col chunk. 8 waves; wave owns 32 rows.
// 3-buffer DMA rotation, counted vmcnt (never 0 in steady state), raw s_barrier.
__global__ __launch_bounds__(512, 4) void k2_main(
        const __hip_bfloat16* __restrict__ lastb,
        const __hip_bfloat16* __restrict__ centb,
        const float* __restrict__ wp,
        float* __restrict__ zsum,
        const float* __restrict__ zdiag,
        int* __restrict__ ticket,
        float* __restrict__ out) {
    const int tid  = threadIdx.x;
    const int lane = tid & 63;
    const int wv   = tid >> 6;                // 0..7
    const int quad = lane >> 4;
    const int l16  = lane & 15;
    const int R0   = blockIdx.x * 256;
    const int C0   = blockIdx.y * 512;
    const float scale = wp[0] * LOG2E;
    // clamp in exp domain (2^z monotone). scale>=0: e >= c0; scale<0: e <= c0.
    const float c0  = __builtin_amdgcn_exp2f(1e-6f * scale);
    const bool  pos = (scale >= 0.f);

    __shared__ uint4 Bs4[3072];   // 3 x 16 KB rotation, XOR chunk-swizzled
    __shared__ float redw[8];
    __shared__ int   lastFlag;
    char* Bsc = (char*)Bs4;

    // stage slab 'slab' (64 cols at C0+slab*64) into rotation buffer buf (0..2).
    // wave wv stages rows wv*8 + i*4 + quad (i=0,1); LDS image = R0 layout.
    auto STAGE = [&](int slab, int buf) {
        const int c0n = C0 + slab * 64;
        char* bufp = Bsc + buf * 16384;
#pragma unroll
        for (int i = 0; i < 2; ++i) {
            const int rr = wv * 8 + i * 4 + quad;
            const int c  = l16 ^ (rr & 15);
            const char* src = (const char*)centb + ((size_t)(c0n + rr) << 8) + (c << 4);
            char* dst = bufp + (wv * 2048 + i * 1024 + lane * 16);
            __builtin_amdgcn_global_load_lds(
                (const __attribute__((address_space(1))) unsigned int*)src,
                (__attribute__((address_space(3))) unsigned int*)dst, 16, 0, 0);
        }
    };

    // prologue: DMA(0) -> buf0; A-frag loads; DMA(1) -> buf1.
    STAGE(0, 0);

    // A fragments (held whole kernel): rows R0 + wv*32 + rt*16 + l16, k = quad*8 + kc*32
    short8 a[2][4];
    {
        const short* ap = (const short*)lastb + (size_t)(R0 + wv * 32 + l16) * DEMB + quad * 8;
#pragma unroll
        for (int rt = 0; rt < 2; ++rt)
#pragma unroll
            for (int kc = 0; kc < 4; ++kc)
                a[rt][kc] = *(const short8*)(ap + rt * 16 * DEMB + kc * 32);
    }

    STAGE(1, 1);

    // swizzled B-fragment byte offsets within a 16-row ntile: row=l16, chunk=(quad+4kc)^l16
    int roff[4];
#pragma unroll
    for (int kc = 0; kc < 4; ++kc)
        roff[kc] = l16 * 256 + (((quad + 4 * kc) ^ l16) << 4);

    float racc[2][4] = {{0.f}};

    for (int it = 0; it < 8; ++it) {
        // wait for DMA(it): at this point issued DMAs are 0..it+1; the 2 newest
        // (DMA(it+1)) may stay in flight -> vmcnt(2). Last iter: nothing newer.
        if (it < 7) {
            asm volatile("s_waitcnt vmcnt(2)" ::: "memory");
        } else {
            asm volatile("s_waitcnt vmcnt(0)" ::: "memory");
        }
        __builtin_amdgcn_sched_barrier(0);
        __builtin_amdgcn_s_barrier();   // all waves' DMA(it) landed; all done reading
                                        // buf[(it-1)%3] (they computed it before arriving)
        if (it < 6) STAGE(it + 2, (it + 2) % 3);   // overwrites buf[(it-1)%3]: safe now

        const char* buf = Bsc + (it % 3) * 16384;
#pragma unroll
        for (int nt = 0; nt < 4; ++nt) {
            short8 b[4];
#pragma unroll
            for (int kc = 0; kc < 4; ++kc)
                b[kc] = *(const short8*)(buf + nt * 4096 + roff[kc]);
            if (pos) {   // wave-uniform: single-sided clamp
#pragma unroll
                for (int rt = 0; rt < 2; ++rt) {
                    f32x4 acc = {0.f, 0.f, 0.f, 0.f};
#pragma unroll
                    for (int kc = 0; kc < 4; ++kc)
                        acc = __builtin_amdgcn_mfma_f32_16x16x32_bf16(a[rt][kc], b[kc], acc, 0, 0, 0);
#pragma unroll
                    for (int r = 0; r < 4; ++r)
                        racc[rt][r] += fmaxf(__builtin_amdgcn_exp2f(acc[r]), c0);
                }
            } else {
#pragma unroll
                for (int rt = 0; rt < 2; ++rt) {
                    f32x4 acc = {0.f, 0.f, 0.f, 0.f};
#pragma unroll
                    for (int kc = 0; kc < 4; ++kc)
                        acc = __builtin_amdgcn_mfma_f32_16x16x32_bf16(a[rt][kc], b[kc], acc, 0, 0, 0);
#pragma unroll
                    for (int r = 0; r < 4; ++r)
                        racc[rt][r] += fminf(__builtin_amdgcn_exp2f(acc[r]), c0);
                }
            }
        }
    }
    // reduce row sums over the 16 l16-lanes holding the same rows
#pragma unroll
    for (int off = 1; off < 16; off <<= 1)
#pragma unroll
        for (int rt = 0; rt < 2; ++rt)
#pragma unroll
            for (int r = 0; r < 4; ++r)
                racc[rt][r] += __shfl_xor(racc[rt][r], off);
    if (l16 == 0) {
#pragma unroll
        for (int rt = 0; rt < 2; ++rt)
#pragma unroll
            for (int r = 0; r < 4; ++r)
                atomicAdd(&zsum[R0 + wv * 32 + rt * 16 + quad * 4 + r], racc[rt][r]);
    }

    // ---- fused loss tail: waitcnt-only ticket (no threadfence / cache maintenance) ----
    // own wave's zsum atomics complete at the coherence point:
    asm volatile("s_waitcnt vmcnt(0)" ::: "memory");
    __syncthreads();                       // => all 8 waves' atomics complete
    if (tid == 0) {
        const int prev = __hip_atomic_fetch_add(ticket, 1, __ATOMIC_RELAXED,
                                                __HIP_MEMORY_SCOPE_AGENT);
        lastFlag = (prev == 32 * 16 - 1);
    }
    __syncthreads();
    if (lastFlag) {                        // block-uniform: last-finishing block
        float v = 0.f;
        for (int n = tid; n < NSPK; n += 512) {
            // fetch_add(0) = coherence-point read of the fully-accumulated zsum
            const float s = __hip_atomic_fetch_add(&zsum[n], 0.f,
                                                   __ATOMIC_RELAXED,
                                                   __HIP_MEMORY_SCOPE_AGENT);
            v += __log2f(s) - zdiag[n];
        }
#pragma unroll
        for (int off = 1; off < 64; off <<= 1) v += __shfl_xor(v, off);
        if (lane == 0) redw[wv] = v;
        __syncthreads();
        if (tid == 0) {
            float t = 0.f;
#pragma unroll
            for (int i = 0; i < 8; ++i) t += redw[i];
            out[0] = t * (LN2 / (float)NSPK);
        }
    }
}

extern "C" void kernel_launch(void* const* d_in, const int* in_sizes, int n_in,
                              void* d_out, int out_size, void* d_ws, size_t ws_size,
                              hipStream_t stream) {
    const float* x = (const float*)d_in[0];
    const float* w = (const float*)d_in[1];
    // b (d_in[2]) cancels analytically — unused.
    float* W = (float*)d_ws;
    __hip_bfloat16* lastb = (__hip_bfloat16*)((char*)d_ws + WS_LASTB);
    __hip_bfloat16* centb = (__hip_bfloat16*)((char*)d_ws + WS_CENTB);

    k1_prep<<<NSPK / 4, 256, 0, stream>>>(x, w, W, lastb, centb);
    k2_main<<<dim3(32, 16), 512, 0, stream>>>(lastb, centb, w, W + WS_ZSUM,
                                              W + WS_ZDIAG, (int*)W + WS_TICKET,
                                              (float*)d_out);
}